// Round 9
// baseline (4420.319 us; speedup 1.0000x reference)
//
#include <hip/hip_runtime.h>

#define B_  32
#define S_  512
#define E_  768
#define HH_ 384
#define G4  1536
#define NT  17

typedef __attribute__((ext_vector_type(8))) short short8;
typedef __attribute__((ext_vector_type(4))) float f32x4;
typedef __attribute__((ext_vector_type(4))) unsigned uint4v;
typedef __attribute__((ext_vector_type(2))) unsigned uint2v;
typedef __attribute__((ext_vector_type(4))) unsigned short ushort4v;

#define SENT 0x7F7F7F7Fu

static __device__ __forceinline__ unsigned short f2bf(float x) {
  unsigned u = __float_as_uint(x);
  u = u + 0x7fffu + ((u >> 16) & 1u);
  return (unsigned short)(u >> 16);
}
static __device__ __forceinline__ float bf2f(unsigned short h) {
  return __uint_as_float(((unsigned)h) << 16);
}
static __device__ __forceinline__ float sigm(float x) {
  return 1.0f / (1.0f + __expf(-x));
}
static __device__ __forceinline__ float tanh_fast(float x) {
  float t = __expf(-2.0f * fabsf(x));
  float r = (1.0f - t) / (1.0f + t);   // stable: t<=1, no overflow
  return copysignf(r, x);
}
// write-through stores to device coherence point (no dirty L2 => no fence/flush needed)
static __device__ __forceinline__ void store_b64_wt(void* p, uint2v v) {
  asm volatile("global_store_dwordx2 %0, %1, off sc0 sc1" :: "v"(p), "v"(v) : "memory");
}

__global__ __launch_bounds__(256) void cvt_bf16(const float* __restrict__ in,
                                                unsigned short* __restrict__ out, int n) {
  for (int i = blockIdx.x * blockDim.x + threadIdx.x; i < n; i += gridDim.x * blockDim.x)
    out[i] = f2bf(in[i]);
}

// ---------------- Input GEMM -> G2 (bf16, frag-order for the lstm consumer) ----------------
// G2 block for (d,s,wi,gate): [mt 2][nt 3][l4 4][l15 16][r 4] ushort = 1536 elems (3 KB).
// Block index = ((d*S+s)*8 + wi)*4 + gate.  (wi owns h-cols [wi*48, wi*48+48))
__global__ __launch_bounds__(256) void gemm_input(
    const unsigned short* __restrict__ embB,   // [32][512][768] bf16
    const unsigned short* __restrict__ WihB,   // [2][1536][768] bf16
    const float* __restrict__ bf, const float* __restrict__ bb,
    unsigned short* __restrict__ G2)
{
  const int d  = blockIdx.z;
  const int n0 = blockIdx.x * 128;
  const int m0 = blockIdx.y * 128;
  const unsigned short* Wd = WihB + (size_t)d * G4 * E_;
  const float* bias = d ? bb : bf;

  __shared__ char As[8192];
  __shared__ char Bs[8192];

  const int tid = threadIdx.x;
  const int wave = tid >> 6, lane = tid & 63;
  const int mq = (wave >> 1) * 64, nq = (wave & 1) * 64;
  const int l4g = lane >> 4, l15g = lane & 15;

  f32x4 acc[4][4] = {};

  for (int k0 = 0; k0 < E_; k0 += 32) {
    __syncthreads();
    #pragma unroll
    for (int i = 0; i < 2; ++i) {
      int chunk = wave * 2 + i;
      int p = chunk * 1024 + lane * 16;            // physical byte this lane fills
      int q = p ^ (((p >> 9) & 1) << 5);           // logical byte (st_16x32 involution)
      int row = q >> 6;                            // 0..127
      int ke  = (q & 63) >> 1;                     // bf16 element 0..31
      { // A: emb row (M ordering = s*32 + b)
        int r = m0 + row; int ss = r >> 5; int bb_ = r & 31;
        const unsigned short* src = embB + ((size_t)bb_ * S_ + ss) * E_ + k0 + ke;
        __builtin_amdgcn_global_load_lds((const __attribute__((address_space(1))) unsigned int*)src,
            (__attribute__((address_space(3))) unsigned int*)(As + chunk * 1024), 16, 0, 0);
      }
      { // B: W_ih rows
        const unsigned short* src = Wd + (size_t)(n0 + row) * E_ + k0 + ke;
        __builtin_amdgcn_global_load_lds((const __attribute__((address_space(1))) unsigned int*)src,
            (__attribute__((address_space(3))) unsigned int*)(Bs + chunk * 1024), 16, 0, 0);
      }
    }
    asm volatile("s_waitcnt vmcnt(0)" ::: "memory");
    __syncthreads();

    short8 af[4], bfm[4];
    int kbyte = ((lane >> 4) * 8) * 2;
    #pragma unroll
    for (int mt = 0; mt < 4; ++mt) {
      int p = (mq + mt * 16 + (lane & 15)) * 64 + kbyte;
      int q = p ^ (((p >> 9) & 1) << 5);
      af[mt] = *(const short8*)(As + q);
    }
    #pragma unroll
    for (int nt = 0; nt < 4; ++nt) {
      int p = (nq + nt * 16 + (lane & 15)) * 64 + kbyte;
      int q = p ^ (((p >> 9) & 1) << 5);
      bfm[nt] = *(const short8*)(Bs + q);
    }
    #pragma unroll
    for (int mt = 0; mt < 4; ++mt)
      #pragma unroll
      for (int nt = 0; nt < 4; ++nt)
        acc[mt][nt] = __builtin_amdgcn_mfma_f32_16x16x32_bf16(af[mt], bfm[nt], acc[mt][nt], 0, 0, 0);
  }

  // epilogue into G2 frag-order; M-quadrant covers TWO s values: s = srow + (mt>>1), slot = mt&1
  const int srow = (m0 + mq) >> 5;   // even
  #pragma unroll
  for (int nt = 0; nt < 4; ++nt) {
    int cb    = n0 + nq + nt * 16;          // lane-independent col base
    int gate  = cb / 384;
    int c384  = cb - gate * 384;
    int wi2   = c384 / 48;
    int ntw   = (c384 - wi2 * 48) >> 4;     // 0..2
    float bv  = bias[cb + l15g];
    #pragma unroll
    for (int mt = 0; mt < 4; ++mt) {
      int s   = srow + (mt >> 1);
      int mtc = mt & 1;
      unsigned short* dst = G2
          + ((((size_t)(d * S_ + s) * 8 + wi2) * 4 + gate) * 1536)
          + (size_t)(((mtc * 3 + ntw) * 4 + l4g) * 64 + l15g * 4);
      ushort4v v;
      #pragma unroll
      for (int r = 0; r < 4; ++r) v[r] = f2bf(acc[mt][nt][r] + bv);
      *(ushort4v*)dst = v;
    }
  }
}

// ---------------- Persistent recurrent LSTM ------------------------------------------------
// 16 WGs x 512 threads: WG w -> dir d = w>>3, wi = w&7 owns h-cols [wi*48, wi*48+48).
// Wave q: gate g = q>>1, K-half kh = q&1. W_hh frags = 18 short8 (register-resident).
// Sync: sentinel-data (hall 0x7F-poisoned; sc0sc1 poll loads = coherence point, matching
// the sc0sc1 write-through stores; plain loads would cache the stale sentinel forever).
// R9: g_lds DOUBLE-BUFFERED by t&1 -> SYNCb removed; ONE barrier per step (SYNCa). Wave
// skew stays <=1 step (bounded by SYNCa) so 2 buffers suffice.
__global__ __launch_bounds__(512, 2) void lstm_rec(
    const unsigned short* __restrict__ WhhB,   // [2][1536][384] bf16
    const unsigned short* __restrict__ hinit,  // [2][32][384] bf16
    const float* __restrict__ c0,              // [2][32][384] fp32
    const unsigned short* __restrict__ G2,     // frag-order bf16 (see gemm)
    unsigned short* __restrict__ hall)         // [2][512][32][384] bf16, 0x7F-poisoned
{
  const int w   = blockIdx.x;        // 0..15
  const int d   = w >> 3;
  const int wi  = w & 7;
  const int j0  = wi * 48;
  const int tid = threadIdx.x, wave = tid >> 6, lane = tid & 63;
  const int g   = wave >> 1;
  const int kh  = wave & 1;
  const int l15 = lane & 15, l4 = lane >> 4;

  __shared__ float g_lds[2][4][2][32][52];   // [buf][gate][khalf][batch][48 + pad 4]

  const int growbase = g * 384 + j0;         // + nt*16 + l15 = W_hh gate-row

  // B-fragments: Bf[nt][j] = W_hh row (growbase+nt*16+l15), k = (kh*6+j)*32 + l4*8
  short8 Bf[3][6];
  {
    const unsigned short* Wd = WhhB + (size_t)d * G4 * HH_;
    #pragma unroll
    for (int nt = 0; nt < 3; ++nt) {
      const unsigned short* rp = Wd + (size_t)(growbase + nt * 16 + l15) * HH_
                                    + (kh * 6) * 32 + l4 * 8;
      #pragma unroll
      for (int j = 0; j < 6; ++j)
        Bf[nt][j] = *(const short8*)(rp + j * 32);
    }
  }

  // update-phase ownership: thread tid<384 owns (batch up_b, 4 h-cols at local up_j)
  const int up_b = tid / 12;
  const int up_j = (tid % 12) * 4;           // local col 0..44
  float c_reg[4];
  if (tid < 384) {
    #pragma unroll
    for (int e = 0; e < 4; ++e)
      c_reg[e] = c0[((size_t)d * B_ + up_b) * HH_ + j0 + up_j + e];
  }

  // G2 for t=0
  ushort4v gpv[6];
  if (kh == 0) {
    int s0 = d ? (S_ - 1) : 0;
    const unsigned short* Gs = G2 + ((((size_t)(d * S_ + s0) * 8 + wi) * 4 + g) * 1536);
    #pragma unroll
    for (int mt = 0; mt < 2; ++mt)
      #pragma unroll
      for (int nt = 0; nt < 3; ++nt)
        gpv[mt * 3 + nt] = *(const ushort4v*)(Gs + ((mt * 3 + nt) * 4 + l4) * 64 + l15 * 4);
  }
  __syncthreads();

  for (int t = 0; t < S_; ++t) {
    const int s = d ? (S_ - 1 - t) : t;
    const int buf = t & 1;

    // keep W_hh fragments live in registers across the loop
    #pragma unroll
    for (int nt = 0; nt < 3; ++nt)
      asm volatile("" : "+v"(Bf[nt][0]), "+v"(Bf[nt][1]), "+v"(Bf[nt][2]),
                        "+v"(Bf[nt][3]), "+v"(Bf[nt][4]), "+v"(Bf[nt][5]));

    // ---- h(t-1): poll-load 12 fragments with sc0 sc1; data = its own flag ----
    const unsigned short* hsrc = (t == 0)
        ? (hinit + (size_t)d * B_ * HH_)
        : (hall + ((size_t)d * S_ + (d ? s + 1 : s - 1)) * B_ * HH_);
    const int kb = l4 * 8;
    uint4v f0[6], f1[6];
    const bool chk = (t > 0);
    while (true) {
      #pragma unroll
      for (int j = 0; j < 6; ++j) {
        const unsigned short* p0 = hsrc + (size_t)l15 * HH_ + (kh * 6 + j) * 32 + kb;
        const unsigned short* p1 = hsrc + (size_t)(16 + l15) * HH_ + (kh * 6 + j) * 32 + kb;
        asm volatile("global_load_dwordx4 %0, %1, off sc0 sc1" : "=v"(f0[j]) : "v"(p0) : "memory");
        asm volatile("global_load_dwordx4 %0, %1, off sc0 sc1" : "=v"(f1[j]) : "v"(p1) : "memory");
      }
      asm volatile("s_waitcnt vmcnt(0)" ::: "memory");
      __builtin_amdgcn_sched_barrier(0);
      if (!chk) break;
      unsigned bad = 0;
      #pragma unroll
      for (int j = 0; j < 6; ++j)
        #pragma unroll
        for (int k2 = 0; k2 < 4; ++k2)
          bad |= (unsigned)(f0[j][k2] == SENT) | (unsigned)(f1[j][k2] == SENT);
      if (!__any((int)bad)) break;
    }

    // ---- MFMAs (acc from zero; G2 folded in at exchange) ----
    f32x4 acc[2][3];
    #pragma unroll
    for (int mt = 0; mt < 2; ++mt)
      #pragma unroll
      for (int nt = 0; nt < 3; ++nt)
        #pragma unroll
        for (int r = 0; r < 4; ++r) acc[mt][nt][r] = 0.0f;

    #pragma unroll
    for (int j = 0; j < 6; ++j) {
      short8 a0 = *(const short8*)&f0[j];
      short8 a1 = *(const short8*)&f1[j];
      #pragma unroll
      for (int nt = 0; nt < 3; ++nt) {
        acc[0][nt] = __builtin_amdgcn_mfma_f32_16x16x32_bf16(a0, Bf[nt][j], acc[0][nt], 0, 0, 0);
        acc[1][nt] = __builtin_amdgcn_mfma_f32_16x16x32_bf16(a1, Bf[nt][j], acc[1][nt], 0, 0, 0);
      }
    }

    // ---- gate exchange through LDS (buffer t&1); kh0 adds the G2 pre-activation ----
    if (kh == 0) {
      #pragma unroll
      for (int mt = 0; mt < 2; ++mt)
        #pragma unroll
        for (int nt = 0; nt < 3; ++nt) {
          ushort4v u = gpv[mt * 3 + nt];
          #pragma unroll
          for (int r = 0; r < 4; ++r)
            g_lds[buf][g][0][mt * 16 + l4 * 4 + r][nt * 16 + l15] = acc[mt][nt][r] + bf2f(u[r]);
        }
    } else {
      #pragma unroll
      for (int mt = 0; mt < 2; ++mt)
        #pragma unroll
        for (int nt = 0; nt < 3; ++nt)
          #pragma unroll
          for (int r = 0; r < 4; ++r)
            g_lds[buf][g][1][mt * 16 + l4 * 4 + r][nt * 16 + l15] = acc[mt][nt][r];
    }

    // ---- G2 prefetch for t+1 (drained only by the NEXT poll's vmcnt, ~a step away) ----
    if (kh == 0 && t + 1 < S_) {
      int s2 = d ? (S_ - 2 - t) : (t + 1);
      const unsigned short* Gs = G2 + ((((size_t)(d * S_ + s2) * 8 + wi) * 4 + g) * 1536);
      #pragma unroll
      for (int mt = 0; mt < 2; ++mt)
        #pragma unroll
        for (int nt = 0; nt < 3; ++nt)
          gpv[mt * 3 + nt] = *(const ushort4v*)(Gs + ((mt * 3 + nt) * 4 + l4) * 64 + l15 * 4);
    }

    // SYNCa: the ONLY barrier per step (lgkm drain + s_barrier; vmcnt untouched)
    __builtin_amdgcn_sched_barrier(0);
    asm volatile("s_waitcnt lgkmcnt(0)" ::: "memory");
    __builtin_amdgcn_s_barrier();
    __builtin_amdgcn_sched_barrier(0);

    // ---- h/c update: 4 cols per thread; h write-through, no ack, no trailing barrier ----
    if (tid < 384) {
      f32x4 iv = *(const f32x4*)&g_lds[buf][0][0][up_b][up_j] + *(const f32x4*)&g_lds[buf][0][1][up_b][up_j];
      f32x4 fv = *(const f32x4*)&g_lds[buf][1][0][up_b][up_j] + *(const f32x4*)&g_lds[buf][1][1][up_b][up_j];
      f32x4 gv = *(const f32x4*)&g_lds[buf][2][0][up_b][up_j] + *(const f32x4*)&g_lds[buf][2][1][up_b][up_j];
      f32x4 ov = *(const f32x4*)&g_lds[buf][3][0][up_b][up_j] + *(const f32x4*)&g_lds[buf][3][1][up_b][up_j];
      unsigned hw[2];
      #pragma unroll
      for (int e2 = 0; e2 < 2; ++e2) {
        unsigned lohi[2];
        #pragma unroll
        for (int k = 0; k < 2; ++k) {
          int e = e2 * 2 + k;
          float c = sigm(fv[e]) * c_reg[e] + sigm(iv[e]) * tanh_fast(gv[e]);
          float h = sigm(ov[e]) * tanh_fast(c);
          c_reg[e] = c;
          lohi[k] = (unsigned)f2bf(h);
        }
        hw[e2] = lohi[0] | (lohi[1] << 16);
      }
      void* pp = (void*)(hall + (((size_t)d * S_ + s) * B_ + up_b) * HH_ + j0 + up_j);
      store_b64_wt(pp, *(uint2v*)hw);
    }
    // no SYNCb: next step uses the other g_lds buffer; skew bounded by SYNCa
  }
}

// ---------------- Logits: one block per s; h staged once in LDS ----------------------------
// Old version re-read 3KB of h per (b,s,n) thread (~856MB redundant traffic, latency-bound).
__global__ __launch_bounds__(256) void logits_k(
    const unsigned short* __restrict__ hall,
    const float* __restrict__ Wtag, const float* __restrict__ btag,
    float* __restrict__ logits)
{
  const int s = blockIdx.x;
  const int tid = threadIdx.x;
  __shared__ unsigned short h2[32][776];   // [batch][768 concat + pad 8] (16B-aligned rows)

  #pragma unroll
  for (int dd = 0; dd < 2; ++dd) {
    const unsigned short* src = hall + ((size_t)dd * S_ + s) * B_ * HH_;
    for (int i = tid; i < (B_ * HH_) / 8; i += 256) {
      short8 v = *(const short8*)(src + i * 8);
      int f = i * 8;
      int b = f / HH_, k = f - b * HH_;
      *(short8*)&h2[b][dd * HH_ + k] = v;
    }
  }
  __syncthreads();

  for (int o = tid; o < B_ * NT; o += 256) {
    int b = o / NT, n = o - b * NT;
    const float* wv = Wtag + (size_t)n * (2 * HH_);
    float acc = btag[n];
    for (int k = 0; k < 2 * HH_; k += 8) {
      short8 hv = *(const short8*)&h2[b][k];
      #pragma unroll
      for (int j = 0; j < 8; ++j) acc += bf2f((unsigned short)hv[j]) * wv[k + j];
    }
    logits[((size_t)b * S_ + s) * NT + n] = acc;
  }
}

// ---------------- Viterbi (faithful: lse alpha + argmax backpointers) ----------------------
// Logits staged in LDS up-front (f32x4 coalesced); transition column in registers.
__global__ __launch_bounds__(64) void viterbi(
    const float* __restrict__ logits,   // [32][512][17]
    const int* __restrict__ mask,       // [32][512]
    const float* __restrict__ trans,    // [17][17]
    float* __restrict__ out)            // [32] scores then [32][512] paths (as float)
{
  const int b = blockIdx.x;
  const int lane = threadIdx.x;
  __shared__ float lgs[S_ * NT];        // 34816 B
  __shared__ float tr[NT * NT];
  __shared__ float alpha[NT];
  __shared__ signed char bp[S_][NT];
  __shared__ int len_s;

  {
    const f32x4* src4 = (const f32x4*)(logits + (size_t)b * S_ * NT);
    f32x4* dst4 = (f32x4*)lgs;
    for (int i = lane; i < (S_ * NT) / 4; i += 64) dst4[i] = src4[i];
  }
  int cnt = 0;
  for (int t = lane; t < S_; t += 64) cnt += mask[(size_t)b * S_ + t];
  #pragma unroll
  for (int o = 32; o > 0; o >>= 1) cnt += __shfl_down(cnt, o);
  if (lane == 0) len_s = cnt;
  for (int i = lane; i < NT * NT; i += 64) tr[i] = trans[i];
  if (lane < NT) alpha[lane] = (lane == 15) ? 0.0f : -1000.0f;
  __syncthreads();
  const int len = len_s;

  float trc[NT];   // my incoming-transition column: trc[p] = trans[p][lane]
  if (lane < NT) {
    #pragma unroll
    for (int p = 0; p < NT; ++p) trc[p] = tr[p * NT + lane];
  }

  for (int t = 0; t < S_; ++t) {
    float na = 0.f; signed char am = 0;
    if (lane < NT) {
      float v[NT];
      float best = -3.4e38f; int arg = 0;
      #pragma unroll
      for (int p = 0; p < NT; ++p) {
        float x = alpha[p] + trc[p];
        v[p] = x;
        if (x > best) { best = x; arg = p; }   // strict > keeps first max (jnp.argmax)
      }
      float ssum = 0.f;
      #pragma unroll
      for (int p = 0; p < NT; ++p) ssum += __expf(v[p] - best);
      na = lgs[t * NT + lane] + best + __logf(ssum);
      am = (signed char)arg;
    }
    __syncthreads();
    if (lane < NT) {
      if (t < len) alpha[lane] = na;
      bp[t][lane] = am;
    }
    __syncthreads();
  }

  if (lane == 0) {
    float fin[NT];
    float best = -3.4e38f; int arg = 0;
    #pragma unroll
    for (int n = 0; n < NT; ++n) {
      fin[n] = alpha[n] + tr[n * NT + 16];
      if (fin[n] > best) { best = fin[n]; arg = n; }
    }
    float ss = 0.f;
    #pragma unroll
    for (int n = 0; n < NT; ++n) ss += __expf(fin[n] - best);
    out[b] = best + __logf(ss);

    int tag = arg;
    float* po = out + B_ + (size_t)b * S_;
    for (int t = S_ - 1; t >= 0; --t) {
      int nt;
      if (t == len - 1) nt = arg;
      else if (t < len - 1) nt = bp[t + 1][tag];
      else nt = tag;
      tag = nt;
      po[t] = (t < len) ? (float)nt : -1.0f;
    }
  }
}

extern "C" void kernel_launch(void* const* d_in, const int* in_sizes, int n_in,
                              void* d_out, int out_size, void* d_ws, size_t ws_size,
                              hipStream_t stream) {
  const float* emb   = (const float*)d_in[0];
  const int*   maskp = (const int*)d_in[1];
  const float* h0    = (const float*)d_in[2];
  const float* c0    = (const float*)d_in[3];
  const float* Wihf  = (const float*)d_in[4];
  const float* Whhf  = (const float*)d_in[5];
  const float* bfp   = (const float*)d_in[6];
  const float* Wihb  = (const float*)d_in[7];
  const float* Whhb  = (const float*)d_in[8];
  const float* bbp   = (const float*)d_in[9];
  const float* Wtag  = (const float*)d_in[10];
  const float* btag  = (const float*)d_in[11];
  const float* trans = (const float*)d_in[12];
  float* out = (float*)d_out;

  char* ws = (char*)d_ws;
  const size_t szG2   = (size_t)2 * S_ * B_ * G4 * 2;      // 100663296 (bf16 frag-order)
  const size_t szEmb  = (size_t)B_ * S_ * E_ * 2;
  const size_t szWih  = (size_t)2 * G4 * E_ * 2;
  const size_t szWhh  = (size_t)2 * G4 * HH_ * 2;
  const size_t szHin  = (size_t)2 * B_ * HH_ * 2;
  const size_t szHall = (size_t)2 * S_ * B_ * HH_ * 2;
  const size_t szLog  = (size_t)B_ * S_ * NT * 4;

  size_t off = 0;
  unsigned short* G2     = (unsigned short*)(ws + off); off += szG2;
  unsigned short* embB   = (unsigned short*)(ws + off); off += szEmb;
  unsigned short* WihB   = (unsigned short*)(ws + off); off += szWih;
  unsigned short* WhhB   = (unsigned short*)(ws + off); off += szWhh;
  unsigned short* hinitB = (unsigned short*)(ws + off); off += szHin;
  unsigned short* hallB  = (unsigned short*)(ws + off); off += szHall;
  float*          logits = (float*)(ws + off);          off += szLog;
  if (ws_size < off) return;

  // poison hall with the sentinel byte (0x7F7F7F7F dwords) - data-embedded sync
  hipMemsetAsync(hallB, 0x7F, szHall, stream);

  cvt_bf16<<<2048, 256, 0, stream>>>(emb,  embB, B_ * S_ * E_);
  cvt_bf16<<<256, 256, 0, stream>>>(Wihf, WihB, G4 * E_);
  cvt_bf16<<<256, 256, 0, stream>>>(Wihb, WihB + (size_t)G4 * E_, G4 * E_);
  cvt_bf16<<<128, 256, 0, stream>>>(Whhf, WhhB, G4 * HH_);
  cvt_bf16<<<128, 256, 0, stream>>>(Whhb, WhhB + (size_t)G4 * HH_, G4 * HH_);
  cvt_bf16<<<48, 256, 0, stream>>>(h0, hinitB, 2 * B_ * HH_);

  gemm_input<<<dim3(G4 / 128, (S_ * B_) / 128, 2), 256, 0, stream>>>(embB, WihB, bfp, bbp, G2);
  lstm_rec<<<16, 512, 0, stream>>>(WhhB, hinitB, c0, G2, hallB);
  logits_k<<<S_, 256, 0, stream>>>(hallB, Wtag, btag, logits);
  viterbi<<<B_, 64, 0, stream>>>(logits, maskp, trans, out);

  (void)in_sizes; (void)n_in; (void)out_size; (void)ws_size;
}

// Round 10
// 3409.191 us; speedup vs baseline: 1.2966x; 1.2966x over previous
//
#include <hip/hip_runtime.h>

#define B_  32
#define S_  512
#define E_  768
#define HH_ 384
#define G4  1536
#define NT  17

typedef __attribute__((ext_vector_type(8))) short short8;
typedef __attribute__((ext_vector_type(4))) float f32x4;
typedef __attribute__((ext_vector_type(4))) unsigned uint4v;
typedef __attribute__((ext_vector_type(2))) unsigned uint2v;
typedef __attribute__((ext_vector_type(4))) unsigned short ushort4v;

#define SENT 0x7F7F7F7Fu

static __device__ __forceinline__ unsigned short f2bf(float x) {
  unsigned u = __float_as_uint(x);
  u = u + 0x7fffu + ((u >> 16) & 1u);
  return (unsigned short)(u >> 16);
}
static __device__ __forceinline__ float bf2f(unsigned short h) {
  return __uint_as_float(((unsigned)h) << 16);
}
static __device__ __forceinline__ float sigm(float x) {
  return 1.0f / (1.0f + __expf(-x));
}
static __device__ __forceinline__ float tanh_fast(float x) {
  float t = __expf(-2.0f * fabsf(x));
  float r = (1.0f - t) / (1.0f + t);   // stable: t<=1, no overflow
  return copysignf(r, x);
}
// write-through stores to device coherence point (no dirty L2 => no fence/flush needed)
static __device__ __forceinline__ void store_b64_wt(void* p, uint2v v) {
  asm volatile("global_store_dwordx2 %0, %1, off sc0 sc1" :: "v"(p), "v"(v) : "memory");
}

__global__ __launch_bounds__(256) void cvt_bf16(const float* __restrict__ in,
                                                unsigned short* __restrict__ out, int n) {
  for (int i = blockIdx.x * blockDim.x + threadIdx.x; i < n; i += gridDim.x * blockDim.x)
    out[i] = f2bf(in[i]);
}

// ================= FUSED KERNEL =================
// blocks 0..15: persistent lstm (R8 structure). blocks 16..1551: gemm_input role —
// each 512-thread block = TWO independent 128x128 tile units (waves 0-3 / 4-7), one per
// direction (half = d), idx = blockIdx-16 -> (mb, nb); d=0 walks s ascending, d=1
// descending so G2 production order matches lstm consumption order. G2 is 0x7F-poisoned;
// gemm writes sc0sc1 write-through; lstm reads sc0sc1 with sentinel-retry (data = flag).
__global__ __launch_bounds__(512, 2) void fused(
    const unsigned short* __restrict__ embB,   // [32][512][768] bf16
    const unsigned short* __restrict__ WihB,   // [2][1536][768] bf16
    const float* __restrict__ bfp, const float* __restrict__ bbp,
    const unsigned short* __restrict__ WhhB,   // [2][1536][384] bf16
    const unsigned short* __restrict__ hinit,  // [2][32][384] bf16
    const float* __restrict__ c0,              // [2][32][384] fp32
    unsigned short* __restrict__ G2,           // frag-order bf16, 0x7F-poisoned
    unsigned short* __restrict__ hall)         // [2][512][32][384] bf16, 0x7F-poisoned
{
  __shared__ __align__(16) char smem[53248];

  const int tid = threadIdx.x, wave = tid >> 6, lane = tid & 63;

  if (blockIdx.x >= 16) {
    // ---------------- GEMM ROLE ----------------
    const int idx  = blockIdx.x - 16;          // 0..1535
    const int half = wave >> 2;                // = direction d
    const int wl   = wave & 3;
    const int d    = half;
    const int mbp  = idx / 12;
    const int nb   = idx - mbp * 12;
    const int mb   = d ? (127 - mbp) : mbp;
    const int n0   = nb * 128;
    const int m0   = mb * 128;
    const unsigned short* Wd = WihB + (size_t)d * G4 * E_;
    const float* bias = d ? bbp : bfp;

    char* As = smem + half * 16384;
    char* Bs = As + 8192;

    const int mq = (wl >> 1) * 64, nq = (wl & 1) * 64;
    const int l4g = lane >> 4, l15g = lane & 15;

    f32x4 acc[4][4] = {};

    for (int k0 = 0; k0 < E_; k0 += 32) {
      __syncthreads();
      #pragma unroll
      for (int i = 0; i < 2; ++i) {
        int chunk = wl * 2 + i;
        int p = chunk * 1024 + lane * 16;          // physical byte this lane fills
        int q = p ^ (((p >> 9) & 1) << 5);         // logical byte (st_16x32 involution)
        int row = q >> 6;
        int ke  = (q & 63) >> 1;
        { // A: emb row (M ordering = s*32 + b)
          int r = m0 + row; int ss = r >> 5; int bb_ = r & 31;
          const unsigned short* src = embB + ((size_t)bb_ * S_ + ss) * E_ + k0 + ke;
          __builtin_amdgcn_global_load_lds((const __attribute__((address_space(1))) unsigned int*)src,
              (__attribute__((address_space(3))) unsigned int*)(As + chunk * 1024), 16, 0, 0);
        }
        { // B: W_ih rows
          const unsigned short* src = Wd + (size_t)(n0 + row) * E_ + k0 + ke;
          __builtin_amdgcn_global_load_lds((const __attribute__((address_space(1))) unsigned int*)src,
              (__attribute__((address_space(3))) unsigned int*)(Bs + chunk * 1024), 16, 0, 0);
        }
      }
      asm volatile("s_waitcnt vmcnt(0)" ::: "memory");
      __syncthreads();

      short8 af[4], bfm[4];
      int kbyte = l4g * 16;
      #pragma unroll
      for (int mt = 0; mt < 4; ++mt) {
        int p = (mq + mt * 16 + l15g) * 64 + kbyte;
        int q = p ^ (((p >> 9) & 1) << 5);
        af[mt] = *(const short8*)(As + q);
      }
      #pragma unroll
      for (int nt = 0; nt < 4; ++nt) {
        int p = (nq + nt * 16 + l15g) * 64 + kbyte;
        int q = p ^ (((p >> 9) & 1) << 5);
        bfm[nt] = *(const short8*)(Bs + q);
      }
      #pragma unroll
      for (int mt = 0; mt < 4; ++mt)
        #pragma unroll
        for (int nt = 0; nt < 4; ++nt)
          acc[mt][nt] = __builtin_amdgcn_mfma_f32_16x16x32_bf16(af[mt], bfm[nt], acc[mt][nt], 0, 0, 0);
    }

    // epilogue -> G2 frag-order, sc0sc1 write-through (visible at coherence point)
    const int srow = (m0 + mq) >> 5;   // even; quadrant covers s = srow, srow+1
    #pragma unroll
    for (int nt = 0; nt < 4; ++nt) {
      int cb    = n0 + nq + nt * 16;
      int gate  = cb / 384;
      int c384  = cb - gate * 384;
      int wi2   = c384 / 48;
      int ntw   = (c384 - wi2 * 48) >> 4;
      float bv  = bias[cb + l15g];
      #pragma unroll
      for (int mt = 0; mt < 4; ++mt) {
        int s   = srow + (mt >> 1);
        int mtc = mt & 1;
        unsigned short* dst = G2
            + ((((size_t)(d * S_ + s) * 8 + wi2) * 4 + gate) * 1536)
            + (size_t)(((mtc * 3 + ntw) * 4 + l4g) * 64 + l15g * 4);
        unsigned lo = (unsigned)f2bf(acc[mt][nt][0] + bv) | ((unsigned)f2bf(acc[mt][nt][1] + bv) << 16);
        unsigned hi = (unsigned)f2bf(acc[mt][nt][2] + bv) | ((unsigned)f2bf(acc[mt][nt][3] + bv) << 16);
        uint2v v; v[0] = lo; v[1] = hi;
        store_b64_wt(dst, v);
      }
    }
    return;
  }

  // ---------------- LSTM ROLE (R8 structure: SYNCa + SYNCb, single g_lds) ----------------
  const int w   = blockIdx.x;        // 0..15
  const int d   = w >> 3;
  const int wi  = w & 7;
  const int j0  = wi * 48;
  const int g   = wave >> 1;
  const int kh  = wave & 1;
  const int l15 = lane & 15, l4 = lane >> 4;

  float (*g_lds)[2][32][52] = (float (*)[2][32][52])smem;   // [gate][khalf][batch][48+4]

  const int growbase = g * 384 + j0;

  // B-fragments: Bf[nt][j] = W_hh row (growbase+nt*16+l15), k = (kh*6+j)*32 + l4*8
  short8 Bf[3][6];
  {
    const unsigned short* Wd = WhhB + (size_t)d * G4 * HH_;
    #pragma unroll
    for (int nt = 0; nt < 3; ++nt) {
      const unsigned short* rp = Wd + (size_t)(growbase + nt * 16 + l15) * HH_
                                    + (kh * 6) * 32 + l4 * 8;
      #pragma unroll
      for (int j = 0; j < 6; ++j)
        Bf[nt][j] = *(const short8*)(rp + j * 32);
    }
  }

  const int up_b = tid / 12;
  const int up_j = (tid % 12) * 4;
  float c_reg[4];
  if (tid < 384) {
    #pragma unroll
    for (int e = 0; e < 4; ++e)
      c_reg[e] = c0[((size_t)d * B_ + up_b) * HH_ + j0 + up_j + e];
  }

  // G2 for t=0: issue sc0sc1 loads (validated at consumption via sentinel)
  uint2v gq[6];
  const unsigned short* Gs0 = G2 + ((((size_t)(d * S_ + (d ? S_ - 1 : 0)) * 8 + wi) * 4 + g) * 1536);
  if (kh == 0) {
    #pragma unroll
    for (int mt = 0; mt < 2; ++mt)
      #pragma unroll
      for (int nt = 0; nt < 3; ++nt) {
        const unsigned short* p = Gs0 + ((mt * 3 + nt) * 4 + l4) * 64 + l15 * 4;
        asm volatile("global_load_dwordx2 %0, %1, off sc0 sc1" : "=v"(gq[mt * 3 + nt]) : "v"(p) : "memory");
      }
  }
  __syncthreads();

  for (int t = 0; t < S_; ++t) {
    const int s = d ? (S_ - 1 - t) : t;

    #pragma unroll
    for (int nt = 0; nt < 3; ++nt)
      asm volatile("" : "+v"(Bf[nt][0]), "+v"(Bf[nt][1]), "+v"(Bf[nt][2]),
                        "+v"(Bf[nt][3]), "+v"(Bf[nt][4]), "+v"(Bf[nt][5]));

    // ---- h(t-1): poll-load 12 fragments with sc0 sc1; data = its own flag ----
    const unsigned short* hsrc = (t == 0)
        ? (hinit + (size_t)d * B_ * HH_)
        : (hall + ((size_t)d * S_ + (d ? s + 1 : s - 1)) * B_ * HH_);
    const int kb = l4 * 8;
    uint4v f0[6], f1[6];
    const bool chk = (t > 0);
    while (true) {
      #pragma unroll
      for (int j = 0; j < 6; ++j) {
        const unsigned short* p0 = hsrc + (size_t)l15 * HH_ + (kh * 6 + j) * 32 + kb;
        const unsigned short* p1 = hsrc + (size_t)(16 + l15) * HH_ + (kh * 6 + j) * 32 + kb;
        asm volatile("global_load_dwordx4 %0, %1, off sc0 sc1" : "=v"(f0[j]) : "v"(p0) : "memory");
        asm volatile("global_load_dwordx4 %0, %1, off sc0 sc1" : "=v"(f1[j]) : "v"(p1) : "memory");
      }
      asm volatile("s_waitcnt vmcnt(0)" ::: "memory");
      __builtin_amdgcn_sched_barrier(0);
      if (!chk) break;
      unsigned bad = 0;
      #pragma unroll
      for (int j = 0; j < 6; ++j)
        #pragma unroll
        for (int k2 = 0; k2 < 4; ++k2)
          bad |= (unsigned)(f0[j][k2] == SENT) | (unsigned)(f1[j][k2] == SENT);
      if (!__any((int)bad)) break;
    }

    // ---- MFMAs (acc from zero; G2 folded in at exchange) ----
    f32x4 acc[2][3];
    #pragma unroll
    for (int mt = 0; mt < 2; ++mt)
      #pragma unroll
      for (int nt = 0; nt < 3; ++nt)
        #pragma unroll
        for (int r = 0; r < 4; ++r) acc[mt][nt][r] = 0.0f;

    #pragma unroll
    for (int j = 0; j < 6; ++j) {
      short8 a0 = *(const short8*)&f0[j];
      short8 a1 = *(const short8*)&f1[j];
      #pragma unroll
      for (int nt = 0; nt < 3; ++nt) {
        acc[0][nt] = __builtin_amdgcn_mfma_f32_16x16x32_bf16(a0, Bf[nt][j], acc[0][nt], 0, 0, 0);
        acc[1][nt] = __builtin_amdgcn_mfma_f32_16x16x32_bf16(a1, Bf[nt][j], acc[1][nt], 0, 0, 0);
      }
    }

    // ---- gate exchange through LDS; kh0 validates (sentinel) + adds the G2 pre-activation --
    if (kh == 0) {
      // G2 loads were drained by the h-poll's vmcnt(0); retry only if sentinel present (early steps)
      const unsigned short* GsC = G2 + ((((size_t)(d * S_ + s) * 8 + wi) * 4 + g) * 1536);
      while (true) {
        unsigned bad = 0;
        #pragma unroll
        for (int j = 0; j < 6; ++j)
          bad |= (unsigned)(gq[j][0] == SENT) | (unsigned)(gq[j][1] == SENT);
        if (!__any((int)bad)) break;
        #pragma unroll
        for (int mt = 0; mt < 2; ++mt)
          #pragma unroll
          for (int nt = 0; nt < 3; ++nt) {
            const unsigned short* p = GsC + ((mt * 3 + nt) * 4 + l4) * 64 + l15 * 4;
            asm volatile("global_load_dwordx2 %0, %1, off sc0 sc1" : "=v"(gq[mt * 3 + nt]) : "v"(p) : "memory");
          }
        asm volatile("s_waitcnt vmcnt(0)" ::: "memory");
        __builtin_amdgcn_sched_barrier(0);
      }
      #pragma unroll
      for (int mt = 0; mt < 2; ++mt)
        #pragma unroll
        for (int nt = 0; nt < 3; ++nt) {
          unsigned q0 = gq[mt * 3 + nt][0], q1 = gq[mt * 3 + nt][1];
          float gv0 = bf2f((unsigned short)(q0 & 0xFFFF));
          float gv1 = bf2f((unsigned short)(q0 >> 16));
          float gv2 = bf2f((unsigned short)(q1 & 0xFFFF));
          float gv3 = bf2f((unsigned short)(q1 >> 16));
          int row = mt * 16 + l4 * 4;
          g_lds[g][0][row + 0][nt * 16 + l15] = acc[mt][nt][0] + gv0;
          g_lds[g][0][row + 1][nt * 16 + l15] = acc[mt][nt][1] + gv1;
          g_lds[g][0][row + 2][nt * 16 + l15] = acc[mt][nt][2] + gv2;
          g_lds[g][0][row + 3][nt * 16 + l15] = acc[mt][nt][3] + gv3;
        }
    } else {
      #pragma unroll
      for (int mt = 0; mt < 2; ++mt)
        #pragma unroll
        for (int nt = 0; nt < 3; ++nt)
          #pragma unroll
          for (int r = 0; r < 4; ++r)
            g_lds[g][1][mt * 16 + l4 * 4 + r][nt * 16 + l15] = acc[mt][nt][r];
    }

    // ---- G2 prefetch for t+1 (sc0sc1; drained by the NEXT step's h-poll vmcnt) ----
    if (kh == 0 && t + 1 < S_) {
      int s2 = d ? (S_ - 2 - t) : (t + 1);
      const unsigned short* Gsn = G2 + ((((size_t)(d * S_ + s2) * 8 + wi) * 4 + g) * 1536);
      #pragma unroll
      for (int mt = 0; mt < 2; ++mt)
        #pragma unroll
        for (int nt = 0; nt < 3; ++nt) {
          const unsigned short* p = Gsn + ((mt * 3 + nt) * 4 + l4) * 64 + l15 * 4;
          asm volatile("global_load_dwordx2 %0, %1, off sc0 sc1" : "=v"(gq[mt * 3 + nt]) : "v"(p) : "memory");
        }
    }

    // SYNCa: raw barrier (lgkm only - vmcnt untouched)
    __builtin_amdgcn_sched_barrier(0);
    asm volatile("s_waitcnt lgkmcnt(0)" ::: "memory");
    __builtin_amdgcn_s_barrier();
    __builtin_amdgcn_sched_barrier(0);

    // ---- h/c update: 4 cols per thread; h write-through ----
    if (tid < 384) {
      f32x4 iv = *(const f32x4*)&g_lds[0][0][up_b][up_j] + *(const f32x4*)&g_lds[0][1][up_b][up_j];
      f32x4 fv = *(const f32x4*)&g_lds[1][0][up_b][up_j] + *(const f32x4*)&g_lds[1][1][up_b][up_j];
      f32x4 gv = *(const f32x4*)&g_lds[2][0][up_b][up_j] + *(const f32x4*)&g_lds[2][1][up_b][up_j];
      f32x4 ov = *(const f32x4*)&g_lds[3][0][up_b][up_j] + *(const f32x4*)&g_lds[3][1][up_b][up_j];
      unsigned hw[2];
      #pragma unroll
      for (int e2 = 0; e2 < 2; ++e2) {
        unsigned lohi[2];
        #pragma unroll
        for (int k = 0; k < 2; ++k) {
          int e = e2 * 2 + k;
          float c = sigm(fv[e]) * c_reg[e] + sigm(iv[e]) * tanh_fast(gv[e]);
          float h = sigm(ov[e]) * tanh_fast(c);
          c_reg[e] = c;
          lohi[k] = (unsigned)f2bf(h);
        }
        hw[e2] = lohi[0] | (lohi[1] << 16);
      }
      void* pp = (void*)(hall + (((size_t)d * S_ + s) * B_ + up_b) * HH_ + j0 + up_j);
      store_b64_wt(pp, *(uint2v*)hw);
    }

    // SYNCb: raw barrier (orders g_lds reads vs next-step writes; vmcnt untouched)
    __builtin_amdgcn_sched_barrier(0);
    asm volatile("s_waitcnt lgkmcnt(0)" ::: "memory");
    __builtin_amdgcn_s_barrier();
    __builtin_amdgcn_sched_barrier(0);
  }
}

// ---------------- Logits: one block per s; h staged once in LDS ----------------------------
__global__ __launch_bounds__(256) void logits_k(
    const unsigned short* __restrict__ hall,
    const float* __restrict__ Wtag, const float* __restrict__ btag,
    float* __restrict__ logits)
{
  const int s = blockIdx.x;
  const int tid = threadIdx.x;
  __shared__ unsigned short h2[32][776];   // [batch][768 concat + pad 8]

  #pragma unroll
  for (int dd = 0; dd < 2; ++dd) {
    const unsigned short* src = hall + ((size_t)dd * S_ + s) * B_ * HH_;
    for (int i = tid; i < (B_ * HH_) / 8; i += 256) {
      short8 v = *(const short8*)(src + i * 8);
      int f = i * 8;
      int b = f / HH_, k = f - b * HH_;
      *(short8*)&h2[b][dd * HH_ + k] = v;
    }
  }
  __syncthreads();

  for (int o = tid; o < B_ * NT; o += 256) {
    int b = o / NT, n = o - b * NT;
    const float* wv = Wtag + (size_t)n * (2 * HH_);
    float acc = btag[n];
    for (int k = 0; k < 2 * HH_; k += 8) {
      short8 hv = *(const short8*)&h2[b][k];
      #pragma unroll
      for (int j = 0; j < 8; ++j) acc += bf2f((unsigned short)hv[j]) * wv[k + j];
    }
    logits[((size_t)b * S_ + s) * NT + n] = acc;
  }
}

// ---------------- Viterbi (faithful: lse alpha + argmax backpointers) ----------------------
__global__ __launch_bounds__(64) void viterbi(
    const float* __restrict__ logits,   // [32][512][17]
    const int* __restrict__ mask,       // [32][512]
    const float* __restrict__ trans,    // [17][17]
    float* __restrict__ out)            // [32] scores then [32][512] paths (as float)
{
  const int b = blockIdx.x;
  const int lane = threadIdx.x;
  __shared__ float lgs[S_ * NT];
  __shared__ float tr[NT * NT];
  __shared__ float alpha[NT];
  __shared__ signed char bp[S_][NT];
  __shared__ int len_s;

  {
    const f32x4* src4 = (const f32x4*)(logits + (size_t)b * S_ * NT);
    f32x4* dst4 = (f32x4*)lgs;
    for (int i = lane; i < (S_ * NT) / 4; i += 64) dst4[i] = src4[i];
  }
  int cnt = 0;
  for (int t = lane; t < S_; t += 64) cnt += mask[(size_t)b * S_ + t];
  #pragma unroll
  for (int o = 32; o > 0; o >>= 1) cnt += __shfl_down(cnt, o);
  if (lane == 0) len_s = cnt;
  for (int i = lane; i < NT * NT; i += 64) tr[i] = trans[i];
  if (lane < NT) alpha[lane] = (lane == 15) ? 0.0f : -1000.0f;
  __syncthreads();
  const int len = len_s;

  float trc[NT];
  if (lane < NT) {
    #pragma unroll
    for (int p = 0; p < NT; ++p) trc[p] = tr[p * NT + lane];
  }

  for (int t = 0; t < S_; ++t) {
    float na = 0.f; signed char am = 0;
    if (lane < NT) {
      float v[NT];
      float best = -3.4e38f; int arg = 0;
      #pragma unroll
      for (int p = 0; p < NT; ++p) {
        float x = alpha[p] + trc[p];
        v[p] = x;
        if (x > best) { best = x; arg = p; }   // strict > keeps first max (jnp.argmax)
      }
      float ssum = 0.f;
      #pragma unroll
      for (int p = 0; p < NT; ++p) ssum += __expf(v[p] - best);
      na = lgs[t * NT + lane] + best + __logf(ssum);
      am = (signed char)arg;
    }
    __syncthreads();
    if (lane < NT) {
      if (t < len) alpha[lane] = na;
      bp[t][lane] = am;
    }
    __syncthreads();
  }

  if (lane == 0) {
    float fin[NT];
    float best = -3.4e38f; int arg = 0;
    #pragma unroll
    for (int n = 0; n < NT; ++n) {
      fin[n] = alpha[n] + tr[n * NT + 16];
      if (fin[n] > best) { best = fin[n]; arg = n; }
    }
    float ss = 0.f;
    #pragma unroll
    for (int n = 0; n < NT; ++n) ss += __expf(fin[n] - best);
    out[b] = best + __logf(ss);

    int tag = arg;
    float* po = out + B_ + (size_t)b * S_;
    for (int t = S_ - 1; t >= 0; --t) {
      int nt;
      if (t == len - 1) nt = arg;
      else if (t < len - 1) nt = bp[t + 1][tag];
      else nt = tag;
      tag = nt;
      po[t] = (t < len) ? (float)nt : -1.0f;
    }
  }
}

extern "C" void kernel_launch(void* const* d_in, const int* in_sizes, int n_in,
                              void* d_out, int out_size, void* d_ws, size_t ws_size,
                              hipStream_t stream) {
  const float* emb   = (const float*)d_in[0];
  const int*   maskp = (const int*)d_in[1];
  const float* h0    = (const float*)d_in[2];
  const float* c0    = (const float*)d_in[3];
  const float* Wihf  = (const float*)d_in[4];
  const float* Whhf  = (const float*)d_in[5];
  const float* bfp   = (const float*)d_in[6];
  const float* Wihb  = (const float*)d_in[7];
  const float* Whhb  = (const float*)d_in[8];
  const float* bbp   = (const float*)d_in[9];
  const float* Wtag  = (const float*)d_in[10];
  const float* btag  = (const float*)d_in[11];
  const float* trans = (const float*)d_in[12];
  float* out = (float*)d_out;

  char* ws = (char*)d_ws;
  const size_t szG2   = (size_t)2 * S_ * B_ * G4 * 2;      // 100663296 (bf16 frag-order)
  const size_t szEmb  = (size_t)B_ * S_ * E_ * 2;
  const size_t szWih  = (size_t)2 * G4 * E_ * 2;
  const size_t szWhh  = (size_t)2 * G4 * HH_ * 2;
  const size_t szHin  = (size_t)2 * B_ * HH_ * 2;
  const size_t szHall = (size_t)2 * S_ * B_ * HH_ * 2;
  const size_t szLog  = (size_t)B_ * S_ * NT * 4;

  size_t off = 0;
  unsigned short* G2     = (unsigned short*)(ws + off); off += szG2;
  unsigned short* embB   = (unsigned short*)(ws + off); off += szEmb;
  unsigned short* WihB   = (unsigned short*)(ws + off); off += szWih;
  unsigned short* WhhB   = (unsigned short*)(ws + off); off += szWhh;
  unsigned short* hinitB = (unsigned short*)(ws + off); off += szHin;
  unsigned short* hallB  = (unsigned short*)(ws + off); off += szHall;
  float*          logits = (float*)(ws + off);          off += szLog;
  if (ws_size < off) return;

  // poison both sentinel-synced buffers (0x7F7F bf16 = 3.4e38, impossible for h and preacts)
  hipMemsetAsync(hallB, 0x7F, szHall, stream);
  hipMemsetAsync(G2,    0x7F, szG2,   stream);

  cvt_bf16<<<2048, 256, 0, stream>>>(emb,  embB, B_ * S_ * E_);
  cvt_bf16<<<256, 256, 0, stream>>>(Wihf, WihB, G4 * E_);
  cvt_bf16<<<256, 256, 0, stream>>>(Wihb, WihB + (size_t)G4 * E_, G4 * E_);
  cvt_bf16<<<128, 256, 0, stream>>>(Whhf, WhhB, G4 * HH_);
  cvt_bf16<<<128, 256, 0, stream>>>(Whhb, WhhB + (size_t)G4 * HH_, G4 * HH_);
  cvt_bf16<<<48, 256, 0, stream>>>(h0, hinitB, 2 * B_ * HH_);

  fused<<<16 + 1536, 512, 0, stream>>>(embB, WihB, bfp, bbp, WhhB, hinitB, c0, G2, hallB);
  logits_k<<<S_, 256, 0, stream>>>(hallB, Wtag, btag, logits);
  viterbi<<<B_, 64, 0, stream>>>(logits, maskp, trans, out);

  (void)in_sizes; (void)n_in; (void)out_size; (void)ws_size;
}